// Round 1
// baseline (1292.196 us; speedup 1.0000x reference)
//
#include <hip/hip_runtime.h>
#include <stdint.h>

// JTMPN on MI355X. bf16 MFMA GEMMs (tolerance is ~2% of output absmax),
// bf16 message table (75.5 MB -> fits Infinity Cache), fused epilogues.

#define MAX_NB 15
#define HID 512
#define NMOLS 1024
#define NA 32768
#define NB 65536
#define NMESS 8192

typedef unsigned short u16;
typedef unsigned int u32;
typedef __bf16 bf16x8 __attribute__((ext_vector_type(8)));
typedef float f32x4 __attribute__((ext_vector_type(4)));

__device__ __forceinline__ u16 f2bf(float f) {
  u32 u = __builtin_bit_cast(u32, f);
  u32 r = (u + 0x7fffu + ((u >> 16) & 1u)) >> 16;
  return (u16)r;
}
__device__ __forceinline__ float bf2f(u16 b) {
  u32 u = ((u32)b) << 16;
  return __builtin_bit_cast(float, u);
}

__device__ __forceinline__ void async16(const u16* g, u16* l) {
  __builtin_amdgcn_global_load_lds(
      (const __attribute__((address_space(1))) u32*)g,
      (__attribute__((address_space(3))) u32*)l, 16, 0, 0);
}

// ---------------- prep: fp32 -> bf16 conversions / transposes ----------------
// regions: tree msg (8192*512), fbonds padded [65536][64], Wi^T [512][64],
// Wh^T [512][512], Wo^T remapped+padded [512][576]
__global__ __launch_bounds__(256) void prep_kernel(
    const float* __restrict__ fbonds, const float* __restrict__ tree,
    const float* __restrict__ Wi, const float* __restrict__ Wh,
    const float* __restrict__ Wo,
    u16* __restrict__ msg, u16* __restrict__ fbpad, u16* __restrict__ wi_t,
    u16* __restrict__ wh_t, u16* __restrict__ wo_t) {
  int t = blockIdx.x * 256 + threadIdx.x;
  const int N0 = NMESS * HID;   // 4194304
  const int N1 = NB * 64;       // 4194304
  const int N2 = 512 * 64;      // 32768
  const int N3 = 512 * 512;     // 262144
  const int N4 = 512 * 576;     // 294912
  if (t < N0) { msg[t] = f2bf(tree[t]); return; }
  t -= N0;
  if (t < N1) {
    int row = t >> 6, c = t & 63;
    fbpad[t] = (c < 40) ? f2bf(fbonds[row * 40 + c]) : (u16)0;
    return;
  }
  t -= N1;
  if (t < N2) {
    int n = t >> 6, k = t & 63;
    wi_t[t] = (k < 40) ? f2bf(Wi[k * 512 + n]) : (u16)0;
    return;
  }
  t -= N2;
  if (t < N3) {
    int n = t >> 9, k = t & 511;
    wh_t[t] = f2bf(Wh[k * 512 + n]);
    return;
  }
  t -= N3;
  if (t < N4) {
    int n = t / 576, k = t - n * 576;
    float v = 0.f;
    if (k < 512) v = Wo[(35 + k) * 512 + n];        // nei part (orig k'=35+k)
    else if (k < 547) v = Wo[(k - 512) * 512 + n];  // fatoms part (orig k'=k-512)
    wo_t[t] = f2bf(v);
    return;
  }
}

// ---------------- gather-sum: wave per row, 16B/lane ----------------
__global__ __launch_bounds__(256) void gather_bonds(
    const u16* __restrict__ msg, const int* __restrict__ bgraph,
    u16* __restrict__ nei) {
  int row = blockIdx.x * 4 + (threadIdx.x >> 6);
  int lane = threadIdx.x & 63;
  const int* idx = bgraph + row * MAX_NB;
  float acc[8] = {0, 0, 0, 0, 0, 0, 0, 0};
#pragma unroll
  for (int j = 0; j < MAX_NB; j++) {
    int id = idx[j];
    uint4 v = *(const uint4*)(msg + (size_t)id * HID + lane * 8);
    acc[0] += bf2f((u16)(v.x & 0xffff)); acc[1] += bf2f((u16)(v.x >> 16));
    acc[2] += bf2f((u16)(v.y & 0xffff)); acc[3] += bf2f((u16)(v.y >> 16));
    acc[4] += bf2f((u16)(v.z & 0xffff)); acc[5] += bf2f((u16)(v.z >> 16));
    acc[6] += bf2f((u16)(v.w & 0xffff)); acc[7] += bf2f((u16)(v.w >> 16));
  }
  uint4 o;
  o.x = (u32)f2bf(acc[0]) | ((u32)f2bf(acc[1]) << 16);
  o.y = (u32)f2bf(acc[2]) | ((u32)f2bf(acc[3]) << 16);
  o.z = (u32)f2bf(acc[4]) | ((u32)f2bf(acc[5]) << 16);
  o.w = (u32)f2bf(acc[6]) | ((u32)f2bf(acc[7]) << 16);
  *(uint4*)(nei + (size_t)row * HID + lane * 8) = o;
}

// atom gather also builds ainput row: [nei(512) | fatoms(35) | zeros(29)]
__global__ __launch_bounds__(256) void gather_atoms(
    const u16* __restrict__ msg, const int* __restrict__ agraph,
    const float* __restrict__ fatoms, u16* __restrict__ ainput) {
  int row = blockIdx.x * 4 + (threadIdx.x >> 6);
  int lane = threadIdx.x & 63;
  const int* idx = agraph + row * MAX_NB;
  float acc[8] = {0, 0, 0, 0, 0, 0, 0, 0};
#pragma unroll
  for (int j = 0; j < MAX_NB; j++) {
    int id = idx[j];
    uint4 v = *(const uint4*)(msg + (size_t)id * HID + lane * 8);
    acc[0] += bf2f((u16)(v.x & 0xffff)); acc[1] += bf2f((u16)(v.x >> 16));
    acc[2] += bf2f((u16)(v.y & 0xffff)); acc[3] += bf2f((u16)(v.y >> 16));
    acc[4] += bf2f((u16)(v.z & 0xffff)); acc[5] += bf2f((u16)(v.z >> 16));
    acc[6] += bf2f((u16)(v.w & 0xffff)); acc[7] += bf2f((u16)(v.w >> 16));
  }
  uint4 o;
  o.x = (u32)f2bf(acc[0]) | ((u32)f2bf(acc[1]) << 16);
  o.y = (u32)f2bf(acc[2]) | ((u32)f2bf(acc[3]) << 16);
  o.z = (u32)f2bf(acc[4]) | ((u32)f2bf(acc[5]) << 16);
  o.w = (u32)f2bf(acc[6]) | ((u32)f2bf(acc[7]) << 16);
  u16* arow = ainput + (size_t)row * 576;
  *(uint4*)(arow + lane * 8) = o;
  float tv = (lane < 35) ? fatoms[(size_t)row * 35 + lane] : 0.f;
  arow[512 + lane] = f2bf(tv);
}

// ---------------- 128x128 bf16 MFMA GEMM, templated epilogue ----------------
// A [M][K] row-major bf16, Bt [512][K] row-major bf16 (i.e. B transposed).
// EPI 0: binput=acc, msg=relu(acc);  EPI 1: msg=relu(acc+binput);
// EPI 2: out[mol] += relu(acc+bias)/le  (in-wave 32-row segment reduce)
template <int EPI>
__global__ __launch_bounds__(256) void gemm_k(
    const u16* __restrict__ A, const u16* __restrict__ Bt, int K,
    u16* __restrict__ binput, u16* __restrict__ msgout,
    const float* __restrict__ bo, const int* __restrict__ scope,
    float* __restrict__ out) {
  __shared__ __align__(16) u16 As[128 * 32];
  __shared__ __align__(16) u16 Bs[128 * 32];
  const int t = threadIdx.x;
  const int lane = t & 63;
  const int w = t >> 6;
  const int wm = w & 1, wn = w >> 1;
  const int mBase = blockIdx.x * 128;
  const int nBase = blockIdx.y * 128;
  const int r = t >> 2;           // 0..63
  const int c8 = (t & 3) * 8;     // 0,8,16,24
  const int q8 = (lane >> 4) * 8; // k-offset of this lane's quad
  const int l15 = lane & 15;

  f32x4 acc[4][4];
#pragma unroll
  for (int i = 0; i < 4; i++)
#pragma unroll
    for (int j = 0; j < 4; j++)
#pragma unroll
      for (int rg = 0; rg < 4; rg++) acc[i][j][rg] = 0.f;

  for (int kb = 0; kb < K; kb += 32) {
    __syncthreads();
    async16(A + (size_t)(mBase + r) * K + kb + c8, As + r * 32 + c8);
    async16(A + (size_t)(mBase + r + 64) * K + kb + c8, As + (r + 64) * 32 + c8);
    async16(Bt + (size_t)(nBase + r) * K + kb + c8, Bs + r * 32 + c8);
    async16(Bt + (size_t)(nBase + r + 64) * K + kb + c8, Bs + (r + 64) * 32 + c8);
    __syncthreads();
    bf16x8 av[4], bv[4];
#pragma unroll
    for (int i = 0; i < 4; i++)
      av[i] = *(const bf16x8*)(As + (wm * 64 + i * 16 + l15) * 32 + q8);
#pragma unroll
    for (int j = 0; j < 4; j++)
      bv[j] = *(const bf16x8*)(Bs + (wn * 64 + j * 16 + l15) * 32 + q8);
#pragma unroll
    for (int i = 0; i < 4; i++)
#pragma unroll
      for (int j = 0; j < 4; j++)
        acc[i][j] = __builtin_amdgcn_mfma_f32_16x16x32_bf16(av[i], bv[j],
                                                            acc[i][j], 0, 0, 0);
  }

  if (EPI == 2) {
    // rows of this wave: wm*64 .. wm*64+63 -> 2 molecules (32 rows each)
#pragma unroll
    for (int m = 0; m < 2; m++) {
      int mol = (mBase + wm * 64 + m * 32) >> 5;
      float inv_le = 1.0f / (float)scope[mol * 2 + 1];
#pragma unroll
      for (int j = 0; j < 4; j++) {
        int col = nBase + wn * 64 + j * 16 + l15;
        float bias = bo[col];
        float s = 0.f;
#pragma unroll
        for (int i = 2 * m; i < 2 * m + 2; i++)
#pragma unroll
          for (int rg = 0; rg < 4; rg++)
            s += fmaxf(acc[i][j][rg] + bias, 0.f);
        s += __shfl_xor(s, 16, 64);
        s += __shfl_xor(s, 32, 64);
        if (lane < 16) out[(size_t)mol * HID + col] = s * inv_le;
      }
    }
  } else {
#pragma unroll
    for (int i = 0; i < 4; i++) {
      int row = mBase + wm * 64 + i * 16 + (lane >> 4) * 4;
#pragma unroll
      for (int j = 0; j < 4; j++) {
        int col = nBase + wn * 64 + j * 16 + l15;
#pragma unroll
        for (int rg = 0; rg < 4; rg++) {
          float v = acc[i][j][rg];
          size_t gi = (size_t)(row + rg) * HID + col;
          if (EPI == 0) {
            binput[gi] = f2bf(v);
            msgout[gi + (size_t)NMESS * HID] = f2bf(fmaxf(v, 0.f));
          } else {
            v += bf2f(binput[gi]);
            msgout[gi + (size_t)NMESS * HID] = f2bf(fmaxf(v, 0.f));
          }
        }
      }
    }
  }
}

// ---------------- launch ----------------
extern "C" void kernel_launch(void* const* d_in, const int* in_sizes, int n_in,
                              void* d_out, int out_size, void* d_ws,
                              size_t ws_size, hipStream_t stream) {
  const float* fatoms = (const float*)d_in[0];
  const float* fbonds = (const float*)d_in[1];
  const int* agraph = (const int*)d_in[2];
  const int* bgraph = (const int*)d_in[3];
  const int* scope = (const int*)d_in[4];
  const float* tree = (const float*)d_in[5];
  const float* Wi = (const float*)d_in[6];
  const float* Wh = (const float*)d_in[7];
  const float* Wo = (const float*)d_in[8];
  const float* bo = (const float*)d_in[9];
  float* out = (float*)d_out;

  char* ws = (char*)d_ws;
  // layout (bytes): msg 75,497,472 | binput 67,108,864 | nei 67,108,864 |
  //                 wi_t 65,536 | wh_t 524,288 | wo_t 589,824  (~211 MB)
  u16* msg = (u16*)(ws);
  u16* binput = (u16*)(ws + 75497472ull);
  u16* nei = (u16*)(ws + 142606336ull);
  u16* wi_t = (u16*)(ws + 209715200ull);
  u16* wh_t = (u16*)(ws + 209780736ull);
  u16* wo_t = (u16*)(ws + 210305024ull);
  u16* fbpad = nei;     // alias: fbpad only needed before first gather
  u16* ainput = binput; // alias: ainput only needed after last binput use

  prep_kernel<<<35072, 256, 0, stream>>>(fbonds, tree, Wi, Wh, Wo, msg, fbpad,
                                         wi_t, wh_t, wo_t);

  dim3 gB(NB / 128, 4); // 512 x 4
  gemm_k<0><<<gB, 256, 0, stream>>>(fbpad, wi_t, 64, binput, msg, nullptr,
                                    nullptr, nullptr);
  for (int d = 0; d < 5; d++) {
    gather_bonds<<<NB / 4, 256, 0, stream>>>(msg, bgraph, nei);
    gemm_k<1><<<gB, 256, 0, stream>>>(nei, wh_t, 512, binput, msg, nullptr,
                                      nullptr, nullptr);
  }
  gather_atoms<<<NA / 4, 256, 0, stream>>>(msg, agraph, fatoms, ainput);
  dim3 gO(NA / 128, 4); // 256 x 4
  gemm_k<2><<<gO, 256, 0, stream>>>(ainput, wo_t, 576, nullptr, nullptr, bo,
                                    scope, out);
}